// Round 6
// baseline (748.441 us; speedup 1.0000x reference)
//
#include <hip/hip_runtime.h>

// Problem: 3-level Haar-style IDWT (g0 128² + bands g3 128², g2 256², g1 512²)
// -> plane (32,1024,1024) f32, then bilinear grid_sample of 2M points -> out (2M,32) f32.
//
// Closed form (length-2 synthesis filters => exactly 1 coeff per band per level per pixel):
// plane[c][y][x] = 0.125*g0[c][y>>3][x>>3]
//               + 0.075*( s3y*g3[c][0] + s3x*g3[c][1] + s3x*s3y*g3[c][2] )[y>>3][x>>3]
//               + 0.100*( s2y*g2[c][0] + s2x*g2[c][1] + s2x*s2y*g2[c][2] )[y>>2][x>>2]
//               + 0.100*( s1y*g1[c][0] + s1x*g1[c][1] + s1x*s1y*g1[c][2] )[y>>1][x>>1]
// signs: s1y from bit0(y), s2y from bit1(y), s3y from bit2(y) (odd index -> +1); same for x.
// Band 0 (LH) carries the y-sign, band 1 (HL) the x-sign, band 2 (HH) both.
// Weights from SCALER=(1.0,0.2,0.4,0.6): 1.0*0.125, 0.6*0.125, 0.4*0.25, 0.2*0.5.
//
// Plane stored CHANNEL-LAST (H, W, C) in d_ws: each bilinear neighbor is one
// contiguous 128B chunk; sampling uses 32 lanes per point (lane == channel).
// idwt uses 8 threads/pixel (thread = pixel x channel-quad) so every wave store
// is a contiguous 4KB burst (fully coalesced float4 per lane).

#define NC 32
#define PW 1024

__global__ __launch_bounds__(256) void idwt_kernel(
    const float* __restrict__ g0, const float* __restrict__ g1,
    const float* __restrict__ g2, const float* __restrict__ g3,
    float* __restrict__ plane)
{
    // Bijective XCD-chunked swizzle (nwg = 32768, divisible by 8): each XCD
    // gets a contiguous chunk of pixel rows, so the y/y+1 re-read of each g1
    // coefficient hits the same XCD's private L2 instead of going out to L3.
    const int nwg = gridDim.x;            // 32768
    const int cpx = nwg >> 3;             // chunk per XCD
    const int bid = (int)blockIdx.x;
    const int swz = (bid & 7) * cpx + (bid >> 3);

    const int tid = swz * 256 + threadIdx.x;
    const int pix = tid >> 3;            // 0 .. 1024*1024-1
    const int c0  = (tid & 7) * 4;       // channel quad: 0,4,...,28
    const int x = pix & (PW - 1);
    const int y = pix >> 10;

    const int i1 = y >> 1, j1 = x >> 1;  // g1 coords (512)
    const int i2 = y >> 2, j2 = x >> 2;  // g2 coords (256)
    const int i3 = y >> 3, j3 = x >> 3;  // g3/g0 coords (128)

    const float s1y = (y & 1) ? 1.f : -1.f;
    const float s1x = (x & 1) ? 1.f : -1.f;
    const float s2y = (y & 2) ? 1.f : -1.f;
    const float s2x = (x & 2) ? 1.f : -1.f;
    const float s3y = (y & 4) ? 1.f : -1.f;
    const float s3x = (x & 4) ? 1.f : -1.f;
    const float s1xy = s1x * s1y;
    const float s2xy = s2x * s2y;
    const float s3xy = s3x * s3y;

    float a[4];
    #pragma unroll
    for (int k = 0; k < 4; ++k) {
        const int c = c0 + k;
        const float* b1 = g1 + ((size_t)(c * 3) * 512 + i1) * 512 + j1;
        const float* b2 = g2 + ((size_t)(c * 3) * 256 + i2) * 256 + j2;
        const float* b3 = g3 + ((size_t)(c * 3) * 128 + i3) * 128 + j3;
        const float v0 = g0[(c * 128 + i3) * 128 + j3];
        const float v1 = s1y * b1[0] + s1x * b1[512 * 512] + s1xy * b1[2 * 512 * 512];
        const float v2 = s2y * b2[0] + s2x * b2[256 * 256] + s2xy * b2[2 * 256 * 256];
        const float v3 = s3y * b3[0] + s3x * b3[128 * 128] + s3xy * b3[2 * 128 * 128];
        a[k] = 0.125f * v0 + 0.075f * v3 + 0.1f * v2 + 0.1f * v1;
    }

    *(float4*)(plane + (size_t)pix * NC + c0) = make_float4(a[0], a[1], a[2], a[3]);
}

__global__ __launch_bounds__(256) void sample_kernel(
    const float* __restrict__ pts, const float* __restrict__ plane,
    float* __restrict__ out, int N)
{
    const int lane  = threadIdx.x & 31;                         // channel
    const int slot  = (blockIdx.x * 256 + threadIdx.x) >> 5;    // point slot
    const int nslot = (gridDim.x * 256) >> 5;

    const float* __restrict__ planeC = plane + lane;  // per-channel base
    float* __restrict__ outC = out + lane;

    for (int n = slot; n < N; n += nslot) {
        // NOTE: __builtin_nontemporal_load rejects HIP_vector_type (float2) —
        // plain load here; pts is only 16MB of ~1.3GB total traffic.
        const float2 p = ((const float2*)pts)[n];
        float xf = fminf(fmaxf((p.x + 1.f) * 0.5f * 1023.f, 0.f), 1023.f);
        float yf = fminf(fmaxf((p.y + 1.f) * 0.5f * 1023.f, 0.f), 1023.f);
        const float x0f = floorf(xf), y0f = floorf(yf);
        const int x0 = (int)x0f, y0 = (int)y0f;
        const int x1 = min(x0 + 1, 1023), y1 = min(y0 + 1, 1023);
        const float wx = xf - x0f, wy = yf - y0f;

        const int r0 = (y0 << 10), r1 = (y1 << 10);
        const float v00 = planeC[(size_t)(r0 + x0) * NC];
        const float v01 = planeC[(size_t)(r0 + x1) * NC];
        const float v10 = planeC[(size_t)(r1 + x0) * NC];
        const float v11 = planeC[(size_t)(r1 + x1) * NC];

        const float w00 = (1.f - wy) * (1.f - wx);
        const float w01 = (1.f - wy) * wx;
        const float w10 = wy * (1.f - wx);
        const float w11 = wy * wx;
        // Output is write-once, never re-read: non-temporal store (scalar float,
        // valid for the builtin) keeps the 128MiB plane resident in the 256MB
        // Infinity Cache for the gathers.
        __builtin_nontemporal_store(v00 * w00 + v01 * w01 + v10 * w10 + v11 * w11,
                                    &outC[(size_t)n * NC]);
    }
}

// ---- Fallback (only if ws too small to hold the plane): fused on-the-fly eval ----
__device__ __forceinline__ float plane_eval(int c, int y, int x,
    const float* __restrict__ g0, const float* __restrict__ g1,
    const float* __restrict__ g2, const float* __restrict__ g3)
{
    const int i1 = y >> 1, j1 = x >> 1;
    const int i2 = y >> 2, j2 = x >> 2;
    const int i3 = y >> 3, j3 = x >> 3;
    const float s1y = (y & 1) ? 1.f : -1.f;
    const float s1x = (x & 1) ? 1.f : -1.f;
    const float s2y = (y & 2) ? 1.f : -1.f;
    const float s2x = (x & 2) ? 1.f : -1.f;
    const float s3y = (y & 4) ? 1.f : -1.f;
    const float s3x = (x & 4) ? 1.f : -1.f;
    const float* b1 = g1 + ((size_t)(c * 3) * 512 + i1) * 512 + j1;
    const float* b2 = g2 + ((size_t)(c * 3) * 256 + i2) * 256 + j2;
    const float* b3 = g3 + ((size_t)(c * 3) * 128 + i3) * 128 + j3;
    const float v0 = g0[(c * 128 + i3) * 128 + j3];
    const float v1 = s1y * b1[0] + s1x * b1[512 * 512] + s1x * s1y * b1[2 * 512 * 512];
    const float v2 = s2y * b2[0] + s2x * b2[256 * 256] + s2x * s2y * b2[2 * 256 * 256];
    const float v3 = s3y * b3[0] + s3x * b3[128 * 128] + s3x * s3y * b3[2 * 128 * 128];
    return 0.125f * v0 + 0.075f * v3 + 0.1f * v2 + 0.1f * v1;
}

__global__ __launch_bounds__(256) void fused_kernel(
    const float* __restrict__ pts,
    const float* __restrict__ g0, const float* __restrict__ g1,
    const float* __restrict__ g2, const float* __restrict__ g3,
    float* __restrict__ out, int N)
{
    const int lane  = threadIdx.x & 31;
    const int slot  = (blockIdx.x * 256 + threadIdx.x) >> 5;
    const int nslot = (gridDim.x * 256) >> 5;

    for (int n = slot; n < N; n += nslot) {
        const float2 p = ((const float2*)pts)[n];
        float xf = fminf(fmaxf((p.x + 1.f) * 0.5f * 1023.f, 0.f), 1023.f);
        float yf = fminf(fmaxf((p.y + 1.f) * 0.5f * 1023.f, 0.f), 1023.f);
        const float x0f = floorf(xf), y0f = floorf(yf);
        const int x0 = (int)x0f, y0 = (int)y0f;
        const int x1 = min(x0 + 1, 1023), y1 = min(y0 + 1, 1023);
        const float wx = xf - x0f, wy = yf - y0f;

        const float v00 = plane_eval(lane, y0, x0, g0, g1, g2, g3);
        const float v01 = plane_eval(lane, y0, x1, g0, g1, g2, g3);
        const float v10 = plane_eval(lane, y1, x0, g0, g1, g2, g3);
        const float v11 = plane_eval(lane, y1, x1, g0, g1, g2, g3);

        out[(size_t)n * NC + lane] =
            v00 * (1.f - wy) * (1.f - wx) + v01 * (1.f - wy) * wx +
            v10 * wy * (1.f - wx)        + v11 * wy * wx;
    }
}

extern "C" void kernel_launch(void* const* d_in, const int* in_sizes, int n_in,
                              void* d_out, int out_size, void* d_ws, size_t ws_size,
                              hipStream_t stream) {
    const float* pts = (const float*)d_in[0];
    const float* g0  = (const float*)d_in[1];
    const float* g1  = (const float*)d_in[2];
    const float* g2  = (const float*)d_in[3];
    const float* g3  = (const float*)d_in[4];
    float* out = (float*)d_out;
    const int N = in_sizes[0] / 2;

    const size_t PLANE_BYTES = (size_t)PW * PW * NC * sizeof(float); // 128 MiB

    if (ws_size >= PLANE_BYTES) {
        float* plane = (float*)d_ws;
        idwt_kernel<<<(PW * PW * 8) / 256, 256, 0, stream>>>(g0, g1, g2, g3, plane);
        sample_kernel<<<8192, 256, 0, stream>>>(pts, plane, out, N);
    } else {
        fused_kernel<<<8192, 256, 0, stream>>>(pts, g0, g1, g2, g3, out, N);
    }
}

// Round 7
// 568.280 us; speedup vs baseline: 1.3170x; 1.3170x over previous
//
#include <hip/hip_runtime.h>

// 3-level Haar-style IDWT -> plane (1024,1024,32) channel-last f32 in d_ws,
// then bilinear grid_sample of 2M points -> out (2M,32) f32.
//
// Closed form per pixel (weights from SCALER=(1.0,0.2,0.4,0.6) x (1/2)^level):
// plane[y][x][c] = 0.125*g0 + 0.075*(s3y*LH3 + s3x*HL3 + s3x*s3y*HH3)
//                + 0.1*(s2y*LH2 + s2x*HL2 + s2x*s2y*HH2)
//                + 0.1*(s1y*LH1 + s1x*HL1 + s1x*s1y*HH1)
// sign bits: level1 y&1/x&1, level2 y&2/x&2, level3 y&4/x&4 (odd index -> +1).
//
// R6 lesson (rocprof): both kernels were latency/issue-bound on scalar 4B
// gathers (idwt 307us @ 654GB/s, VALUBusy 11%, VGPR 28). Fix = more bytes per
// instruction: idwt thread = (channel, y, 8-x-octet) with float4/float2 coeff
// loads (10 loads per 8 px vs 80); sample = 8 lanes/point float4 gathers
// (0.5 gather instrs/point vs 4).

#define NC 32
#define PW 1024

typedef float f32x2 __attribute__((ext_vector_type(2)));
typedef float f32x4 __attribute__((ext_vector_type(4)));

__global__ __launch_bounds__(256) void idwt_kernel(
    const float* __restrict__ g0, const float* __restrict__ g1,
    const float* __restrict__ g2, const float* __restrict__ g3,
    float* __restrict__ plane)
{
    // 16384 blocks: block -> (y row, 64-x segment). XCD-chunked swizzle keeps
    // y/y+1 (which share g1/g2/g3 rows) on the same XCD's L2.
    const int bid = (int)blockIdx.x;
    const int swz = ((bid & 7) << 11) + (bid >> 3);   // 2048 blocks per XCD
    const int y    = swz >> 4;
    const int xseg = swz & 15;
    const int c = threadIdx.x & 31;                   // channel
    const int o = threadIdx.x >> 5;                   // x octet 0..7
    const int x0 = (xseg << 6) + (o << 3);            // first of 8 pixels

    const int i1 = y >> 1, i2 = y >> 2, i3 = y >> 3;
    const int j1 = x0 >> 1, j2 = x0 >> 2, j3 = x0 >> 3;

    const float s1y = (y & 1) ? 1.f : -1.f;
    const float s2y = (y & 2) ? 1.f : -1.f;
    const float s3y = (y & 4) ? 1.f : -1.f;

    // g1[c][band][512][512]: 3 x float4 (j1..j1+3)
    const size_t b1 = ((size_t)c * 3) * 262144 + (size_t)i1 * 512 + j1;
    const f32x4 A0 = *(const f32x4*)(g1 + b1);
    const f32x4 A1 = *(const f32x4*)(g1 + b1 + 262144);
    const f32x4 A2 = *(const f32x4*)(g1 + b1 + 524288);
    // g2[c][band][256][256]: 3 x float2
    const size_t b2 = ((size_t)c * 3) * 65536 + (size_t)i2 * 256 + j2;
    const f32x2 B0 = *(const f32x2*)(g2 + b2);
    const f32x2 B1 = *(const f32x2*)(g2 + b2 + 65536);
    const f32x2 B2 = *(const f32x2*)(g2 + b2 + 131072);
    // g3[c][band][128][128] + g0[c][128][128]: 4 scalars
    const size_t b3 = ((size_t)c * 3) * 16384 + (size_t)i3 * 128 + j3;
    const float C0 = g3[b3];
    const float C1 = g3[b3 + 16384];
    const float C2 = g3[b3 + 32768];
    const float v0 = g0[(size_t)c * 16384 + (size_t)i3 * 128 + j3];

    // Fold y-signs once; x-signs are compile-time per unrolled k.
    const f32x4 u1 = s1y * A0;
    const f32x4 t1 = A1 + s1y * A2;
    const f32x2 u2 = s2y * B0;
    const f32x2 t2 = B1 + s2y * B2;
    const float u3 = s3y * C0;
    const float t3 = C1 + s3y * C2;
    const float base = 0.125f * v0 + 0.075f * u3;

    float a[8];
    #pragma unroll
    for (int k = 0; k < 8; ++k) {
        const float sx1 = (k & 1) ? 1.f : -1.f;
        const float sx2 = (k & 2) ? 1.f : -1.f;
        const float sx3 = (k & 4) ? 1.f : -1.f;
        a[k] = base + (0.075f * sx3) * t3
             + 0.1f * (u2[k >> 2] + sx2 * t2[k >> 2])
             + 0.1f * (u1[k >> 1] + sx1 * t1[k >> 1]);
    }

    float* dst = plane + ((size_t)y * PW + x0) * NC + c;
    #pragma unroll
    for (int k = 0; k < 8; ++k) dst[(size_t)k * NC] = a[k];
}

__global__ __launch_bounds__(256) void sample_kernel(
    const float* __restrict__ pts, const float* __restrict__ plane,
    float* __restrict__ out, int N)
{
    // 8 lanes per point: q = channel quad (float4 each), g = point-in-wave.
    const int lane = threadIdx.x & 63;
    const int g = lane >> 3, q = lane & 7;
    const int wid = (int)((blockIdx.x * 256 + threadIdx.x) >> 6);
    const int nw  = (int)((gridDim.x * 256) >> 6);

    for (int n = wid * 8 + g; n < N; n += nw * 8) {
        const f32x2 p = __builtin_nontemporal_load((const f32x2*)pts + n);
        const float xf = fminf(fmaxf((p[0] + 1.f) * 0.5f * 1023.f, 0.f), 1023.f);
        const float yf = fminf(fmaxf((p[1] + 1.f) * 0.5f * 1023.f, 0.f), 1023.f);
        const float x0f = floorf(xf), y0f = floorf(yf);
        const int x0 = (int)x0f, y0 = (int)y0f;
        const int x1 = min(x0 + 1, 1023), y1 = min(y0 + 1, 1023);
        const float wx = xf - x0f, wy = yf - y0f;

        const int r0 = y0 << 10, r1 = y1 << 10;
        const f32x4 v00 = *(const f32x4*)(plane + (size_t)(r0 + x0) * NC + q * 4);
        const f32x4 v01 = *(const f32x4*)(plane + (size_t)(r0 + x1) * NC + q * 4);
        const f32x4 v10 = *(const f32x4*)(plane + (size_t)(r1 + x0) * NC + q * 4);
        const f32x4 v11 = *(const f32x4*)(plane + (size_t)(r1 + x1) * NC + q * 4);

        const float w00 = (1.f - wy) * (1.f - wx);
        const float w01 = (1.f - wy) * wx;
        const float w10 = wy * (1.f - wx);
        const float w11 = wy * wx;
        const f32x4 res = v00 * w00 + v01 * w01 + v10 * w10 + v11 * w11;

        // Write-once output: NT store keeps the plane L3-resident.
        __builtin_nontemporal_store(res, (f32x4*)(out + (size_t)n * NC + q * 4));
    }
}

// ---- Fallback (only if ws too small to hold the plane): fused on-the-fly eval ----
__device__ __forceinline__ float plane_eval(int c, int y, int x,
    const float* __restrict__ g0, const float* __restrict__ g1,
    const float* __restrict__ g2, const float* __restrict__ g3)
{
    const int i1 = y >> 1, j1 = x >> 1;
    const int i2 = y >> 2, j2 = x >> 2;
    const int i3 = y >> 3, j3 = x >> 3;
    const float s1y = (y & 1) ? 1.f : -1.f;
    const float s1x = (x & 1) ? 1.f : -1.f;
    const float s2y = (y & 2) ? 1.f : -1.f;
    const float s2x = (x & 2) ? 1.f : -1.f;
    const float s3y = (y & 4) ? 1.f : -1.f;
    const float s3x = (x & 4) ? 1.f : -1.f;
    const float* b1 = g1 + ((size_t)(c * 3) * 512 + i1) * 512 + j1;
    const float* b2 = g2 + ((size_t)(c * 3) * 256 + i2) * 256 + j2;
    const float* b3 = g3 + ((size_t)(c * 3) * 128 + i3) * 128 + j3;
    const float v0 = g0[(c * 128 + i3) * 128 + j3];
    const float v1 = s1y * b1[0] + s1x * b1[512 * 512] + s1x * s1y * b1[2 * 512 * 512];
    const float v2 = s2y * b2[0] + s2x * b2[256 * 256] + s2x * s2y * b2[2 * 256 * 256];
    const float v3 = s3y * b3[0] + s3x * b3[128 * 128] + s3x * s3y * b3[2 * 128 * 128];
    return 0.125f * v0 + 0.075f * v3 + 0.1f * v2 + 0.1f * v1;
}

__global__ __launch_bounds__(256) void fused_kernel(
    const float* __restrict__ pts,
    const float* __restrict__ g0, const float* __restrict__ g1,
    const float* __restrict__ g2, const float* __restrict__ g3,
    float* __restrict__ out, int N)
{
    const int lane  = threadIdx.x & 31;
    const int slot  = (blockIdx.x * 256 + threadIdx.x) >> 5;
    const int nslot = (gridDim.x * 256) >> 5;

    for (int n = slot; n < N; n += nslot) {
        const float2 p = ((const float2*)pts)[n];
        float xf = fminf(fmaxf((p.x + 1.f) * 0.5f * 1023.f, 0.f), 1023.f);
        float yf = fminf(fmaxf((p.y + 1.f) * 0.5f * 1023.f, 0.f), 1023.f);
        const float x0f = floorf(xf), y0f = floorf(yf);
        const int x0 = (int)x0f, y0 = (int)y0f;
        const int x1 = min(x0 + 1, 1023), y1 = min(y0 + 1, 1023);
        const float wx = xf - x0f, wy = yf - y0f;

        const float v00 = plane_eval(lane, y0, x0, g0, g1, g2, g3);
        const float v01 = plane_eval(lane, y0, x1, g0, g1, g2, g3);
        const float v10 = plane_eval(lane, y1, x0, g0, g1, g2, g3);
        const float v11 = plane_eval(lane, y1, x1, g0, g1, g2, g3);

        out[(size_t)n * NC + lane] =
            v00 * (1.f - wy) * (1.f - wx) + v01 * (1.f - wy) * wx +
            v10 * wy * (1.f - wx)        + v11 * wy * wx;
    }
}

extern "C" void kernel_launch(void* const* d_in, const int* in_sizes, int n_in,
                              void* d_out, int out_size, void* d_ws, size_t ws_size,
                              hipStream_t stream) {
    const float* pts = (const float*)d_in[0];
    const float* g0  = (const float*)d_in[1];
    const float* g1  = (const float*)d_in[2];
    const float* g2  = (const float*)d_in[3];
    const float* g3  = (const float*)d_in[4];
    float* out = (float*)d_out;
    const int N = in_sizes[0] / 2;

    const size_t PLANE_BYTES = (size_t)PW * PW * NC * sizeof(float); // 128 MiB

    if (ws_size >= PLANE_BYTES) {
        float* plane = (float*)d_ws;
        idwt_kernel<<<16384, 256, 0, stream>>>(g0, g1, g2, g3, plane);
        sample_kernel<<<8192, 256, 0, stream>>>(pts, plane, out, N);
    } else {
        fused_kernel<<<8192, 256, 0, stream>>>(pts, g0, g1, g2, g3, out, N);
    }
}